// Round 3
// baseline (420.184 us; speedup 1.0000x reference)
//
#include <hip/hip_runtime.h>
#include <cstdint>
#include <cstddef>

// Problem constants
#define NN   4096   // N
#define FIN  512    // F_IN
#define FOUT 256    // F_OUT
#define BK   256    // K-chunk per LDS stage
#define LDSK 264    // BK + 8 shorts pad
// C = 4, channel-last everywhere -> 4 consecutive floats per (..) element
//
// Algebra: x3 is constant along C -> FFT(x3) lives at freq 0 only, so
// h = x @ Wsum (channel-independent); then out = (sum_c adjs) @ h + bias.
// Two real GEMMs, no FFT.

typedef short bf16x8 __attribute__((ext_vector_type(8)));
typedef float f32x4  __attribute__((ext_vector_type(4)));
typedef float f32x2  __attribute__((ext_vector_type(2)));

__device__ __forceinline__ unsigned short f2bf(float f) {
    union { float f; unsigned u; } v; v.f = f;
    unsigned r = v.u + 0x7FFFu + ((v.u >> 16) & 1u);   // RNE
    return (unsigned short)(r >> 16);
}
__device__ __forceinline__ unsigned pack2(float a, float b) {
    return (unsigned)f2bf(a) | ((unsigned)f2bf(b) << 16);
}

// ---------------------------------------------------------------------------
// Kernel 0: Wsum_T[r][j] = sum_c weight[j][r][c]   (bf16, [256][512] K-major)
// ---------------------------------------------------------------------------
__global__ __launch_bounds__(256) void k_prep_wsum(const f32x4* __restrict__ w4,
                                                   unsigned short* __restrict__ wsumT) {
    int t = blockIdx.x * 256 + threadIdx.x;   // 0 .. 131071
    int r = t & (FOUT - 1);
    int j = t >> 8;
    f32x4 v = w4[j * FOUT + r];               // coalesced across r
    wsumT[r * FIN + j] = f2bf((v.x + v.y) + (v.z + v.w));
}

// ---------------------------------------------------------------------------
// GEMM: 16 rows x 256 cols per block, 512 threads (8 waves), BK=256,
// bf16 MFMA 16x16x32, LDS double-buffered A (1 barrier/chunk), full-chunk
// register prefetch of A and B re-issued right after consumption so 1-2
// chunks stay in flight per CU (transfer-bound, not latency-bound).
// MODE 0: A = x (fp32, row stride 512). Epilogue: write H_T bf16 [256][4096].
// MODE 1: A = sum_c adjs (f32x4/elem, row stride 4096). Epilogue: +bias.
// ---------------------------------------------------------------------------
template<int K, int MODE>
__global__ __launch_bounds__(512, 2) void k_gemm16(
    const void* __restrict__ Aptr,
    const unsigned short* __restrict__ Bt,   // [256][K] bf16, K-major (L2-resident)
    unsigned short* __restrict__ Ht,         // MODE 0 output
    const f32x4* __restrict__ bias4,         // MODE 1
    f32x4* __restrict__ out4)                // MODE 1
{
    constexpr int NCHUNK = K / BK;           // MODE1: 16, MODE0: 2 (both even)
    __shared__ unsigned short Abf[2][16 * LDSK];

    const int tid  = threadIdx.x;
    const int lane = tid & 63;
    const int wave = tid >> 6;         // 0..7
    const int quad = lane >> 4;        // 0..3
    const int l15  = lane & 15;
    const int i0   = blockIdx.x * 16;

    const int si  = tid >> 5;          // staging row 0..15
    const int c32 = tid & 31;          // staging column group

    f32x4 acc0 = {0.f, 0.f, 0.f, 0.f};
    f32x4 acc1 = {0.f, 0.f, 0.f, 0.f};

    auto loadA = [&](int c, f32x4* pa, f32x2* pf) {
        const int kb = c * BK;
        if (MODE == 0) {
            const float* xp = (const float*)Aptr + (size_t)(i0 + si) * FIN + kb + c32 * 2;
#pragma unroll
            for (int u = 0; u < 4; ++u)
                pf[u] = __builtin_nontemporal_load((const f32x2*)(xp + u * 64));
        } else {
            const f32x4* ap = (const f32x4*)Aptr + (size_t)(i0 + si) * NN + kb + c32 * 2;
#pragma unroll
            for (int u = 0; u < 4; ++u) {
                pa[2 * u]     = __builtin_nontemporal_load(ap + u * 64);
                pa[2 * u + 1] = __builtin_nontemporal_load(ap + u * 64 + 1);
            }
        }
    };
    auto writeA = [&](int b, const f32x4* pa, const f32x2* pf) {
        unsigned* dst = (unsigned*)&Abf[b][si * LDSK + c32 * 2];
        if (MODE == 0) {
#pragma unroll
            for (int u = 0; u < 4; ++u)
                dst[u * 32] = pack2(pf[u].x, pf[u].y);
        } else {
#pragma unroll
            for (int u = 0; u < 4; ++u) {
                f32x4 p0 = pa[2 * u], p1 = pa[2 * u + 1];
                dst[u * 32] = pack2((p0.x + p0.y) + (p0.z + p0.w),
                                    (p1.x + p1.y) + (p1.z + p1.w));
            }
        }
    };
    auto loadB = [&](int c, bf16x8* b0, bf16x8* b1) {
        const unsigned short* p0 = Bt + (size_t)(wave * 32 + l15) * K + c * BK + quad * 8;
#pragma unroll
        for (int s = 0; s < 8; ++s) {
            b0[s] = *(const bf16x8*)(p0 + s * 32);
            b1[s] = *(const bf16x8*)(p0 + (size_t)16 * K + s * 32);
        }
    };
    auto compute = [&](int b, const bf16x8* b0, const bf16x8* b1) {
        const unsigned short* arow = &Abf[b][l15 * LDSK + quad * 8];
#pragma unroll
        for (int s = 0; s < 8; ++s) {
            bf16x8 a = *(const bf16x8*)(arow + s * 32);
            acc0 = __builtin_amdgcn_mfma_f32_16x16x32_bf16(a, b0[s], acc0, 0, 0, 0);
            acc1 = __builtin_amdgcn_mfma_f32_16x16x32_bf16(a, b1[s], acc1, 0, 0, 0);
        }
    };

    f32x4 paX[8], paY[8];
    f32x2 pfX[4], pfY[4];
    bf16x8 b0X[8], b1X[8], b0Y[8], b1Y[8];

    loadA(0, paX, pfX); loadB(0, b0X, b1X);
    loadA(1, paY, pfY); loadB(1, b0Y, b1Y);

    for (int c = 0; c < NCHUNK; c += 2) {
        // ---- chunk c (buffer 0, set X) ----
        writeA(0, paX, pfX);
        { int cn = (c + 2 < NCHUNK) ? c + 2 : 0; loadA(cn, paX, pfX); }
        __syncthreads();
        compute(0, b0X, b1X);
        { int cn = (c + 2 < NCHUNK) ? c + 2 : 0; loadB(cn, b0X, b1X); }

        // ---- chunk c+1 (buffer 1, set Y) ----
        writeA(1, paY, pfY);
        { int cn = (c + 3 < NCHUNK) ? c + 3 : 1; loadA(cn, paY, pfY); }
        __syncthreads();
        compute(1, b0Y, b1Y);
        { int cn = (c + 3 < NCHUNK) ? c + 3 : 1; loadB(cn, b0Y, b1Y); }
    }

    // -------- epilogue. D layout: col = lane&15, row = quad*4 + reg --------
    if (MODE == 0) {
        const int n  = wave * 32 + l15;
        const int ib = i0 + quad * 4;
        ushort4 h;
        h.x = f2bf(acc0[0]); h.y = f2bf(acc0[1]); h.z = f2bf(acc0[2]); h.w = f2bf(acc0[3]);
        *(ushort4*)(Ht + (size_t)n * NN + ib) = h;
        h.x = f2bf(acc1[0]); h.y = f2bf(acc1[1]); h.z = f2bf(acc1[2]); h.w = f2bf(acc1[3]);
        *(ushort4*)(Ht + (size_t)(n + 16) * NN + ib) = h;
    } else {
        const int col = wave * 32 + l15;
        const int ib  = i0 + quad * 4;
#pragma unroll
        for (int r = 0; r < 4; ++r) {
            size_t idx = (size_t)(ib + r) * FOUT + col;
            f32x4 bv = __builtin_nontemporal_load(bias4 + idx);
            float s  = acc0[r];
            f32x4 o; o.x = s + bv.x; o.y = s + bv.y; o.z = s + bv.z; o.w = s + bv.w;
            __builtin_nontemporal_store(o, out4 + idx);
            f32x4 bv1 = __builtin_nontemporal_load(bias4 + idx + 16);
            float s1  = acc1[r];
            f32x4 o1; o1.x = s1 + bv1.x; o1.y = s1 + bv1.y; o1.z = s1 + bv1.z; o1.w = s1 + bv1.w;
            __builtin_nontemporal_store(o1, out4 + idx + 16);
        }
    }
}

// ---------------------------------------------------------------------------
extern "C" void kernel_launch(void* const* d_in, const int* in_sizes, int n_in,
                              void* d_out, int out_size, void* d_ws, size_t ws_size,
                              hipStream_t stream) {
    const float* x     = (const float*)d_in[0];    // [4096][512] f32
    const void*  adjs  = d_in[1];                  // [4096][4096][4] f32
    const f32x4* w4    = (const f32x4*)d_in[2];    // [512][256] x f32x4
    const f32x4* bias4 = (const f32x4*)d_in[3];    // [4096][256] x f32x4
    f32x4*       out4  = (f32x4*)d_out;            // [4096][256] x f32x4

    unsigned short* wsumT = (unsigned short*)d_ws;                                   // 256 KiB
    unsigned short* Ht    = (unsigned short*)((char*)d_ws + (size_t)FOUT * FIN * 2); // 2 MiB

    // Wsum^T (bf16, K-major)
    k_prep_wsum<<<(FIN * FOUT) / 256, 256, 0, stream>>>(w4, wsumT);
    // H^T = (x @ Wsum)^T  (bf16, [256][4096])
    k_gemm16<FIN, 0><<<NN / 16, 512, 0, stream>>>((const void*)x, wsumT, Ht, nullptr, nullptr);
    // out = Asum @ H + bias
    k_gemm16<NN, 1><<<NN / 16, 512, 0, stream>>>(adjs, Ht, nullptr, bias4, out4);
}

// Round 4
// 396.872 us; speedup vs baseline: 1.0587x; 1.0587x over previous
//
#include <hip/hip_runtime.h>
#include <cstdint>
#include <cstddef>

// Problem constants
#define NN   4096   // N
#define FIN  512    // F_IN
#define FOUT 256    // F_OUT
// C = 4, channel-last -> 4 consecutive floats per element
//
// Algebra: x3 is constant along C -> FFT(x3) lives at freq 0 only, so
// h = x @ Wsum (channel-independent); then out = (sum_c adjs) @ h + bias.
// Two real GEMMs, no FFT.
//
// Big GEMM: 64 rows x 256 cols x K/4 per block (grid 256). Split-K partials
// in f32 -> reduce kernel adds + bias. kq = bid&3 so all blocks on one XCD
// (round-robin %8 dispatch) share one 512 KiB B-slice -> B stays L2-resident
// instead of 512 MiB of HBM re-reads (the R1 bottleneck).

typedef short bf16x8 __attribute__((ext_vector_type(8)));
typedef float f32x4  __attribute__((ext_vector_type(4)));
typedef float f32x2  __attribute__((ext_vector_type(2)));

__device__ __forceinline__ unsigned short f2bf(float f) {
    union { float f; unsigned u; } v; v.f = f;
    unsigned r = v.u + 0x7FFFu + ((v.u >> 16) & 1u);   // RNE
    return (unsigned short)(r >> 16);
}
__device__ __forceinline__ unsigned pack2(float a, float b) {
    return (unsigned)f2bf(a) | ((unsigned)f2bf(b) << 16);
}

// ---------------------------------------------------------------------------
// Kernel 0: Wsum_T[r][j] = sum_c weight[j][r][c]   (bf16, [256][512] K-major)
// ---------------------------------------------------------------------------
__global__ __launch_bounds__(256) void k_prep_wsum(const f32x4* __restrict__ w4,
                                                   unsigned short* __restrict__ wsumT) {
    int t = blockIdx.x * 256 + threadIdx.x;
    int r = t & (FOUT - 1);
    int j = t >> 8;
    f32x4 v = w4[j * FOUT + r];
    wsumT[r * FIN + j] = f2bf((v.x + v.y) + (v.z + v.w));
}

// ---------------------------------------------------------------------------
// Kernel 1: H^T = (x @ Wsum)^T, bf16 [256][4096]. 16 rows x 256 cols/block,
// BK=64, 8 chunks. (R1-proven structure.)
// ---------------------------------------------------------------------------
__global__ __launch_bounds__(512) void k_gemm_h(const float* __restrict__ x,
                                                const unsigned short* __restrict__ Bt,
                                                unsigned short* __restrict__ Ht) {
    __shared__ unsigned short Abf[16 * 72];
    const int tid  = threadIdx.x;
    const int lane = tid & 63;
    const int wave = tid >> 6;
    const int quad = lane >> 4;
    const int l15  = lane & 15;
    const int i0   = blockIdx.x * 16;
    const int si   = tid >> 5;
    const int sk   = (tid & 31) * 2;

    f32x4 acc0 = {0.f, 0.f, 0.f, 0.f};
    f32x4 acc1 = {0.f, 0.f, 0.f, 0.f};

    f32x2 pf;
    bf16x8 bp00, bp01, bp10, bp11;

    auto loadA = [&](int c) {
        pf = *(const f32x2*)(x + (size_t)(i0 + si) * FIN + c * 64 + sk);
    };
    auto loadB = [&](int c, bf16x8& b00, bf16x8& b01, bf16x8& b10, bf16x8& b11) {
        const unsigned short* p0 = Bt + (size_t)(wave * 32 + l15) * FIN + c * 64 + quad * 8;
        b00 = *(const bf16x8*)(p0);
        b01 = *(const bf16x8*)(p0 + 32);
        const unsigned short* p1 = p0 + (size_t)16 * FIN;
        b10 = *(const bf16x8*)(p1);
        b11 = *(const bf16x8*)(p1 + 32);
    };

    loadA(0);
    loadB(0, bp00, bp01, bp10, bp11);

    for (int c = 0; c < FIN / 64; ++c) {
        __syncthreads();
        *(unsigned*)&Abf[si * 72 + sk] = pack2(pf.x, pf.y);
        __syncthreads();

        bf16x8 bc00 = bp00, bc01 = bp01, bc10 = bp10, bc11 = bp11;
        if (c + 1 < FIN / 64) {
            loadA(c + 1);
            loadB(c + 1, bp00, bp01, bp10, bp11);
        }
        bf16x8 a0 = *(const bf16x8*)&Abf[l15 * 72 + quad * 8];
        bf16x8 a1 = *(const bf16x8*)&Abf[l15 * 72 + 32 + quad * 8];

        acc0 = __builtin_amdgcn_mfma_f32_16x16x32_bf16(a0, bc00, acc0, 0, 0, 0);
        acc0 = __builtin_amdgcn_mfma_f32_16x16x32_bf16(a1, bc01, acc0, 0, 0, 0);
        acc1 = __builtin_amdgcn_mfma_f32_16x16x32_bf16(a0, bc10, acc1, 0, 0, 0);
        acc1 = __builtin_amdgcn_mfma_f32_16x16x32_bf16(a1, bc11, acc1, 0, 0, 0);
    }

    // D layout: col = lane&15, row = quad*4 + reg
    const int n  = wave * 32 + l15;
    const int ib = i0 + quad * 4;
    ushort4 h;
    h.x = f2bf(acc0[0]); h.y = f2bf(acc0[1]); h.z = f2bf(acc0[2]); h.w = f2bf(acc0[3]);
    *(ushort4*)(Ht + (size_t)n * NN + ib) = h;
    h.x = f2bf(acc1[0]); h.y = f2bf(acc1[1]); h.z = f2bf(acc1[2]); h.w = f2bf(acc1[3]);
    *(ushort4*)(Ht + (size_t)(n + 16) * NN + ib) = h;
}

// ---------------------------------------------------------------------------
// Kernel 2: big GEMM partials. Block = 64 rows x 256 cols x K=1024.
// grid 256: kq = bid & 3 (K-quarter), rg = bid >> 2 (row group).
// BK=64, 16 chunks, LDS double-buffered A (sum_c adjs -> bf16).
// P[kq][row][col] f32.
// ---------------------------------------------------------------------------
#define LD 72   // LDS row stride in shorts (144 B: 16B-aligned for b128)
__global__ __launch_bounds__(512) void k_gemm_big(const f32x4* __restrict__ adjs4,
                                                  const unsigned short* __restrict__ Bt,
                                                  float* __restrict__ P) {
    __shared__ unsigned short Abf[2][64 * LD];

    const int tid  = threadIdx.x;
    const int lane = tid & 63;
    const int wave = tid >> 6;
    const int quad = lane >> 4;
    const int l15  = lane & 15;

    const int kq   = blockIdx.x & 3;
    const int rg   = blockIdx.x >> 2;
    const int row0 = rg * 64;
    const size_t kbase = (size_t)kq * 1024;

    const int sr = tid >> 3;        // staging row 0..63
    const int sc = tid & 7;         // staging col group

    f32x4 acc[4][2];
#pragma unroll
    for (int m = 0; m < 4; ++m)
#pragma unroll
        for (int n = 0; n < 2; ++n)
            acc[m][n] = (f32x4){0.f, 0.f, 0.f, 0.f};

    f32x4 pa[8];                    // A prefetch: 8 f32x4 / thread / chunk
    bf16x8 pb[2][2];                // B prefetch: [ntile][kstep]

    auto loadA = [&](int c) {
        const f32x4* ap = adjs4 + (size_t)(row0 + sr) * NN + kbase + c * 64;
#pragma unroll
        for (int u = 0; u < 4; ++u) {
            pa[2 * u]     = __builtin_nontemporal_load(ap + sc * 2 + u * 16);
            pa[2 * u + 1] = __builtin_nontemporal_load(ap + sc * 2 + u * 16 + 1);
        }
    };
    auto writeA = [&](int b) {
        unsigned* dst = (unsigned*)&Abf[b][sr * LD + sc * 2];
#pragma unroll
        for (int u = 0; u < 4; ++u) {
            f32x4 p0 = pa[2 * u], p1 = pa[2 * u + 1];
            dst[u * 8] = pack2((p0.x + p0.y) + (p0.z + p0.w),
                               (p1.x + p1.y) + (p1.z + p1.w));
        }
    };
    auto loadB = [&](int c) {
#pragma unroll
        for (int n = 0; n < 2; ++n) {
            const unsigned short* p = Bt + (size_t)(wave * 32 + n * 16 + l15) * NN
                                        + kbase + c * 64 + quad * 8;
            pb[n][0] = *(const bf16x8*)p;
            pb[n][1] = *(const bf16x8*)(p + 32);
        }
    };

    loadA(0);
    loadB(0);

    for (int c = 0; c < 16; ++c) {
        const int b = c & 1;
        writeA(b);
        if (c + 1 < 16) loadA(c + 1);       // in flight during compute
        __syncthreads();

        bf16x8 bc[2][2] = {{pb[0][0], pb[0][1]}, {pb[1][0], pb[1][1]}};
        if (c + 1 < 16) loadB(c + 1);

#pragma unroll
        for (int s = 0; s < 2; ++s) {
#pragma unroll
            for (int m = 0; m < 4; ++m) {
                bf16x8 a = *(const bf16x8*)&Abf[b][(m * 16 + l15) * LD + s * 32 + quad * 8];
                acc[m][0] = __builtin_amdgcn_mfma_f32_16x16x32_bf16(a, bc[0][s], acc[m][0], 0, 0, 0);
                acc[m][1] = __builtin_amdgcn_mfma_f32_16x16x32_bf16(a, bc[1][s], acc[m][1], 0, 0, 0);
            }
        }
        __syncthreads();   // protect buf b before it's rewritten at c+2
    }

    // epilogue: P[kq][row][col], D layout col = lane&15, row = quad*4 + reg
    float* p = P + (size_t)kq * NN * FOUT;
#pragma unroll
    for (int m = 0; m < 4; ++m) {
#pragma unroll
        for (int n = 0; n < 2; ++n) {
            const int col = wave * 32 + n * 16 + l15;
#pragma unroll
            for (int r = 0; r < 4; ++r) {
                const int row = row0 + m * 16 + quad * 4 + r;
                p[(size_t)row * FOUT + col] = acc[m][n][r];
            }
        }
    }
}

// ---------------------------------------------------------------------------
// Kernel 3: out = (P0+P1+P2+P3) + bias
// ---------------------------------------------------------------------------
__global__ __launch_bounds__(256) void k_reduce(const float* __restrict__ P,
                                                const f32x4* __restrict__ bias4,
                                                f32x4* __restrict__ out4) {
    const int idx = blockIdx.x * 256 + threadIdx.x;     // (i,col) flat, 1M total
    const size_t STR = (size_t)NN * FOUT;
    float s = (P[idx] + P[idx + STR]) + (P[idx + 2 * STR] + P[idx + 3 * STR]);
    f32x4 bv = bias4[idx];
    f32x4 o;
    o.x = s + bv.x; o.y = s + bv.y; o.z = s + bv.z; o.w = s + bv.w;
    out4[idx] = o;
}

// ---------------------------------------------------------------------------
extern "C" void kernel_launch(void* const* d_in, const int* in_sizes, int n_in,
                              void* d_out, int out_size, void* d_ws, size_t ws_size,
                              hipStream_t stream) {
    const float* x     = (const float*)d_in[0];    // [4096][512] f32
    const f32x4* adjs4 = (const f32x4*)d_in[1];    // [4096][4096] x f32x4 (C=4)
    const f32x4* w4    = (const f32x4*)d_in[2];    // [512][256] x f32x4
    const f32x4* bias4 = (const f32x4*)d_in[3];    // [4096][256] x f32x4
    f32x4*       out4  = (f32x4*)d_out;            // [4096][256] x f32x4

    char* ws = (char*)d_ws;
    unsigned short* wsumT = (unsigned short*)ws;                       // 256 KiB
    unsigned short* Ht    = (unsigned short*)(ws + 262144);            // 2 MiB
    float*          Pp    = (float*)(ws + 262144 + 2097152);           // 16 MiB

    k_prep_wsum<<<(FIN * FOUT) / 256, 256, 0, stream>>>(w4, wsumT);
    k_gemm_h<<<NN / 16, 512, 0, stream>>>(x, wsumT, Ht);
    k_gemm_big<<<256, 512, 0, stream>>>(adjs4, Ht, Pp);
    k_reduce<<<(NN * FOUT) / 256, 256, 0, stream>>>(Pp, bias4, out4);
}